// Round 9
// baseline (189.007 us; speedup 1.0000x reference)
//
#include <hip/hip_runtime.h>
#include <math.h>

#define T_DIM 2048
#define B_DIM 2
#define E_DIM 1024
#define K_DIM 64
#define H_DIM 16
#define R_DIM (T_DIM * B_DIM)   // 4096 rows, row r = t*B + b
#define WROWS 2176              // Wq(1024) + Wv(1024) + Wk(64) + pad(64)
#define NTILE 136               // 16*17/2 causal (qt,st) tile pairs

typedef __bf16 bf16x8 __attribute__((ext_vector_type(8)));
typedef __bf16 bf16x4 __attribute__((ext_vector_type(4)));
typedef float f32x4 __attribute__((ext_vector_type(4)));

#define GLD16(gptr, lptr)                                                      \
    __builtin_amdgcn_global_load_lds(                                          \
        (const __attribute__((address_space(1))) void*)(gptr),                 \
        (__attribute__((address_space(3))) void*)(lptr), 16, 0, 0)

// ---------------------------------------------------------------------------
// Fused fp32->bf16 conversion: blocks [0,2048) convert x (4M elems);
// blocks [2048,3136) convert W-concat [Wq;Wv;Wk;pad] (2176*1024 elems).
// ---------------------------------------------------------------------------
__global__ __launch_bounds__(256) void cvt_all(const float* __restrict__ X,
                                               const float* __restrict__ Wq,
                                               const float* __restrict__ Wv,
                                               const float* __restrict__ Wk,
                                               __bf16* __restrict__ XB,
                                               __bf16* __restrict__ WB) {
    const size_t nq = (size_t)1024 * 1024;
    const size_t nk = (size_t)64 * 1024;
    bf16x8 o;
    if (blockIdx.x < 2048) {
        size_t g = ((size_t)blockIdx.x * 256 + threadIdx.x) * 8;
        float4 a = *(const float4*)&X[g];
        float4 b = *(const float4*)&X[g + 4];
        o[0] = (__bf16)a.x; o[1] = (__bf16)a.y; o[2] = (__bf16)a.z; o[3] = (__bf16)a.w;
        o[4] = (__bf16)b.x; o[5] = (__bf16)b.y; o[6] = (__bf16)b.z; o[7] = (__bf16)b.w;
        *(bf16x8*)&XB[g] = o;
    } else {
        size_t g = ((size_t)(blockIdx.x - 2048) * 256 + threadIdx.x) * 8;
        if (g < 2 * nq + nk) {
            const float* src;
            size_t off;
            if (g < nq)          { src = Wq; off = g; }
            else if (g < 2 * nq) { src = Wv; off = g - nq; }
            else                 { src = Wk; off = g - 2 * nq; }
            float4 a = *(const float4*)&src[off];
            float4 b = *(const float4*)&src[off + 4];
            o[0] = (__bf16)a.x; o[1] = (__bf16)a.y; o[2] = (__bf16)a.z; o[3] = (__bf16)a.w;
            o[4] = (__bf16)b.x; o[5] = (__bf16)b.y; o[6] = (__bf16)b.z; o[7] = (__bf16)b.w;
        } else {
#pragma unroll
            for (int i = 0; i < 8; ++i) o[i] = (__bf16)0.f;
        }
        *(bf16x8*)&WB[g] = o;
    }
}

// ---------------------------------------------------------------------------
// bf16 MFMA GEMM v2: C[4096 x 2112] = XB[4096x1024] @ WB[.x1024]^T
// 128x64 tiles, BK=32 -> grid (32, 33) = 1056 blocks (~4.1/CU, ~5 co-resident)
// so staging-barrier drains of one block overlap MFMA of others.
// Col tiles 0-15 -> Qb bf16(+bq); 16-31 -> Vb bf16(+bv); 32 -> Kr fp32(+bk).
// ---------------------------------------------------------------------------
__global__ __launch_bounds__(256) void gemm_mfma(const __bf16* __restrict__ XB,
                                                 const __bf16* __restrict__ WB,
                                                 const float* __restrict__ bq,
                                                 const float* __restrict__ bv,
                                                 const float* __restrict__ bk,
                                                 __bf16* __restrict__ Qb,
                                                 __bf16* __restrict__ Vb,
                                                 float* __restrict__ Kr) {
    __shared__ __bf16 Als[128 * 32];   // 8 KB
    __shared__ __bf16 Bls[64 * 32];    // 4 KB
    const int tid = threadIdx.x;
    const int lane = tid & 63;
    const int w = tid >> 6;
    const int wm = (w & 1) * 64;       // wave row offset
    const int wn = (w >> 1) * 32;      // wave col offset
    const int rBase = blockIdx.x * 128;
    const int cBase = blockIdx.y * 64;

    // A staging: 512 chunks of 16B (row=c>>2, koff=(c&3)*8); B: 256 chunks.
    const int cA0 = tid, cA1 = tid + 256;
    const __bf16* gA0 = XB + (size_t)(rBase + (cA0 >> 2)) * E_DIM + (cA0 & 3) * 8;
    const __bf16* gA1 = XB + (size_t)(rBase + (cA1 >> 2)) * E_DIM + (cA1 & 3) * 8;
    const __bf16* gB0 = WB + (size_t)(cBase + (tid >> 2)) * E_DIM + (tid & 3) * 8;
    __bf16* lA0 = Als + cA0 * 8;
    __bf16* lA1 = Als + cA1 * 8;
    __bf16* lB0 = Bls + tid * 8;

    const int fr = lane & 15;
    const int fk = (lane >> 4) * 8;
    const __bf16* aF = Als + (wm + fr) * 32 + fk;
    const __bf16* bF = Bls + (wn + fr) * 32 + fk;

    f32x4 acc[4][2] = {};

    for (int kk = 0; kk < E_DIM; kk += 32) {
        __syncthreads();
        GLD16(gA0 + kk, lA0);
        GLD16(gA1 + kk, lA1);
        GLD16(gB0 + kk, lB0);
        __syncthreads();

        bf16x8 af[4], bfr[2];
#pragma unroll
        for (int mt = 0; mt < 4; ++mt) af[mt] = *(const bf16x8*)(aF + mt * 16 * 32);
#pragma unroll
        for (int nt = 0; nt < 2; ++nt) bfr[nt] = *(const bf16x8*)(bF + nt * 16 * 32);
#pragma unroll
        for (int mt = 0; mt < 4; ++mt)
#pragma unroll
            for (int nt = 0; nt < 2; ++nt)
                acc[mt][nt] = __builtin_amdgcn_mfma_f32_16x16x32_bf16(
                    af[mt], bfr[nt], acc[mt][nt], 0, 0, 0);
    }

    // epilogue: C/D layout col=lane&15, row=(lane>>4)*4+reg
    const int row0 = rBase + wm + (lane >> 4) * 4;
    const int colLoc = wn + (lane & 15);
    if (cBase < 2048) {
        const float* bias;
        __bf16* Cout;
        int colBase;
        if (cBase < 1024) { bias = bq; Cout = Qb; colBase = cBase; }
        else              { bias = bv; Cout = Vb; colBase = cBase - 1024; }
#pragma unroll
        for (int mt = 0; mt < 4; ++mt)
#pragma unroll
            for (int nt = 0; nt < 2; ++nt) {
                int cc = colBase + colLoc + nt * 16;
                float bb = bias[cc];
#pragma unroll
                for (int r = 0; r < 4; ++r)
                    Cout[(size_t)(row0 + mt * 16 + r) * E_DIM + cc] =
                        (__bf16)(acc[mt][nt][r] + bb);
            }
    } else {
        // k tile: 64 cols exactly, fp32 out stride 64
#pragma unroll
        for (int mt = 0; mt < 4; ++mt)
#pragma unroll
            for (int nt = 0; nt < 2; ++nt) {
                int cc = colLoc + nt * 16;
                float bb = bk[cc];
#pragma unroll
                for (int r = 0; r < 4; ++r)
                    Kr[(size_t)(row0 + mt * 16 + r) * K_DIM + cc] =
                        acc[mt][nt][r] + bb;
            }
    }
}

// ---------------------------------------------------------------------------
// Fused row epilogues, one block per row r = t*B + b:
//  - qn[b][t][k] = mean_h softmax_k(qb[r, h*64+k])
//  - knb[b][t][k] = LN64(kraw[r])
//  - stats[r] = {mean, rsqrt(var+eps)} of vb[r]
// ---------------------------------------------------------------------------
__global__ __launch_bounds__(256) void rowops(const __bf16* __restrict__ Qb,
                                              const float* __restrict__ Kraw,
                                              const __bf16* __restrict__ Vb,
                                              const float* __restrict__ kg,
                                              const float* __restrict__ kb,
                                              __bf16* __restrict__ QNB,
                                              __bf16* __restrict__ KNB,
                                              float2* __restrict__ ST) {
    const int r = blockIdx.x;
    const int tid = threadIdx.x;
    const int lane = tid & 63, wv = tid >> 6;
    const int t = r >> 1, b = r & 1;
    __shared__ float redq[4][64];
    __shared__ float redv[2][4];

    float acc = 0.f;
#pragma unroll
    for (int h4 = 0; h4 < 4; ++h4) {
        int h = wv * 4 + h4;
        float v = (float)Qb[(size_t)r * 1024 + h * 64 + lane];
        float m = v;
#pragma unroll
        for (int off = 32; off; off >>= 1) m = fmaxf(m, __shfl_xor(m, off));
        float e = expf(v - m);
        float ssum = e;
#pragma unroll
        for (int off = 32; off; off >>= 1) ssum += __shfl_xor(ssum, off);
        acc += e / ssum;
    }
    redq[wv][lane] = acc;

    {
        bf16x4 v4 = *(const bf16x4*)&Vb[(size_t)r * 1024 + tid * 4];
        float a = (float)v4[0], c = (float)v4[1], d = (float)v4[2], e = (float)v4[3];
        float s = a + c + d + e;
        float s2 = a * a + c * c + d * d + e * e;
#pragma unroll
        for (int off = 32; off; off >>= 1) {
            s += __shfl_xor(s, off);
            s2 += __shfl_xor(s2, off);
        }
        if (lane == 0) { redv[0][wv] = s; redv[1][wv] = s2; }
    }
    __syncthreads();

    if (tid < 64) {
        float s = redq[0][tid] + redq[1][tid] + redq[2][tid] + redq[3][tid];
        QNB[((size_t)b * T_DIM + t) * K_DIM + tid] = (__bf16)(s * (1.f / 16.f));
    } else if (tid < 128) {
        float v = Kraw[(size_t)r * K_DIM + lane];
        float s = v, s2 = v * v;
#pragma unroll
        for (int off = 32; off; off >>= 1) {
            s += __shfl_xor(s, off);
            s2 += __shfl_xor(s2, off);
        }
        float mean = s * (1.f / 64.f);
        float var = s2 * (1.f / 64.f) - mean * mean;
        float inv = rsqrtf(var + 1e-5f);
        KNB[((size_t)b * T_DIM + t) * K_DIM + lane] =
            (__bf16)((v - mean) * inv * kg[lane] + kb[lane]);
    } else if (tid == 128) {
        float s = redv[0][0] + redv[0][1] + redv[0][2] + redv[0][3];
        float s2 = redv[1][0] + redv[1][1] + redv[1][2] + redv[1][3];
        float mean = s * (1.f / 1024.f);
        float var = s2 * (1.f / 1024.f) - mean * mean;
        ST[r] = make_float2(mean, rsqrtf(var + 1e-5f));
    }
}

// ---------------------------------------------------------------------------
// Fused LN + transpose: vb bf16 [t*2+b][e] -> VT bf16 [b][e][t].
// ---------------------------------------------------------------------------
__global__ __launch_bounds__(256) void transpose_lnv(const __bf16* __restrict__ VB,
                                                     const float2* __restrict__ ST,
                                                     const float* __restrict__ gamma,
                                                     const float* __restrict__ beta,
                                                     __bf16* __restrict__ VT) {
    __shared__ float tile[64][65];
    const int tb = blockIdx.x, eb = blockIdx.y, b = blockIdx.z;
    const int tid = threadIdx.x;
#pragma unroll
    for (int j = 0; j < 2; ++j) {
        int idx = tid + j * 256;           // 512 chunks of 8 bf16
        int tl = idx >> 3, e8 = idx & 7;
        int r = (tb * 64 + tl) * B_DIM + b;
        float2 st = ST[r];
        bf16x8 v = *(const bf16x8*)&VB[(size_t)r * E_DIM + eb * 64 + e8 * 8];
#pragma unroll
        for (int i = 0; i < 8; ++i)
            tile[tl][e8 * 8 + i] = ((float)v[i] - st.x) * st.y;
    }
    __syncthreads();
#pragma unroll
    for (int j = 0; j < 4; ++j) {
        int idx = tid + j * 256;           // 1024 groups of 4 t
        int e = idx >> 4, t4 = idx & 15;
        float g = gamma[eb * 64 + e], bb = beta[eb * 64 + e];
        bf16x4 o;
#pragma unroll
        for (int i = 0; i < 4; ++i) o[i] = (__bf16)(tile[t4 * 4 + i][e] * g + bb);
        *(bf16x4*)&VT[((size_t)b * E_DIM + eb * 64 + e) * T_DIM + tb * 64 + t4 * 4] = o;
    }
}

// ---------------------------------------------------------------------------
// scoreK: all causal 128x128 score tiles, masked, bf16, LDS-staged operands.
// ---------------------------------------------------------------------------
__global__ __launch_bounds__(256) void scoreK(const __bf16* __restrict__ QNB,
                                              const __bf16* __restrict__ KNB,
                                              __bf16* __restrict__ Pg) {
    __shared__ __bf16 qns[128 * 72];   // 18 KB
    __shared__ __bf16 kns[128 * 72];   // 18 KB
    const int tileId = blockIdx.x;
    const int b = blockIdx.y;
    int qt = 0, rem = tileId;
    while (rem > qt) { rem -= (qt + 1); ++qt; }
    const int st = rem;
    const int tid = threadIdx.x;
    const int lane = tid & 63;
    const int w = tid >> 6;
    const int qL = lane & 15;
    const int quad = lane >> 4;

    const __bf16* qsrc = QNB + ((size_t)b * T_DIM + qt * 128) * K_DIM;
    const __bf16* ksrc = KNB + ((size_t)b * T_DIM + st * 128) * K_DIM;
#pragma unroll
    for (int j = 0; j < 4; ++j) {
        int idx = tid + j * 256;
        int row = idx >> 3, k8 = idx & 7;
        *(bf16x8*)&qns[row * 72 + k8 * 8] = *(const bf16x8*)&qsrc[row * K_DIM + k8 * 8];
        *(bf16x8*)&kns[row * 72 + k8 * 8] = *(const bf16x8*)&ksrc[row * K_DIM + k8 * 8];
    }
    __syncthreads();

    f32x4 acc[8][2] = {};
#pragma unroll
    for (int kit = 0; kit < 2; ++kit) {
        bf16x8 bfr[2];
#pragma unroll
        for (int nt = 0; nt < 2; ++nt) {
            int q = w * 32 + nt * 16 + qL;
            bfr[nt] = *(const bf16x8*)&qns[q * 72 + kit * 32 + quad * 8];
        }
#pragma unroll
        for (int mt = 0; mt < 8; ++mt) {
            bf16x8 af = *(const bf16x8*)&kns[(mt * 16 + qL) * 72 + kit * 32 + quad * 8];
#pragma unroll
            for (int nt = 0; nt < 2; ++nt)
                acc[mt][nt] = __builtin_amdgcn_mfma_f32_16x16x32_bf16(
                    af, bfr[nt], acc[mt][nt], 0, 0, 0);
        }
    }
    __bf16* pb = Pg + ((size_t)(b * NTILE + tileId)) * 128 * 128;
#pragma unroll
    for (int mt = 0; mt < 8; ++mt)
#pragma unroll
        for (int nt = 0; nt < 2; ++nt) {
            int q = w * 32 + nt * 16 + qL;
            int s0 = mt * 16 + quad * 4;
            bf16x4 o;
#pragma unroll
            for (int r = 0; r < 4; ++r) {
                float val = acc[mt][nt][r];
                if (qt == st && (s0 + r) > q) val = 0.f;
                o[r] = (__bf16)val;
            }
            *(bf16x4*)&pb[(size_t)q * 128 + s0] = o;
        }
}

// ---------------------------------------------------------------------------
// flashPV v3: out[t,b,e] = rsqrt(t+1) * sum_{st<=qt} sum_s P[q,s]·v[s,e]
// Grid (8 pairs, 16 es, 2 b); pair p covers qt=p then 15-p (uniform 17 iters).
// Register-prefetch double buffer: next tile's global loads are issued before
// the MFMA burst, ds_written after -> load latency hides under MFMA.
// ---------------------------------------------------------------------------
__global__ __launch_bounds__(256) void flashPV(const __bf16* __restrict__ Pg,
                                               const __bf16* __restrict__ VT,
                                               float* __restrict__ OUT) {
    __shared__ __align__(16) __bf16 vts[64 * 136];    // 17.4 KB (+ epilogue scratch)
    __shared__ __align__(16) __bf16 ps[128 * 136];    // 34.8 KB
    const int p = blockIdx.x;
    const int es = blockIdx.y;
    const int b = blockIdx.z;
    const int tid = threadIdx.x;
    const int lane = tid & 63;
    const int w = tid >> 6;
    const int qL = lane & 15;
    const int quad = lane >> 4;

    const __bf16* vtBase = VT + ((size_t)b * E_DIM + es * 64) * T_DIM;

    for (int ph = 0; ph < 2; ++ph) {
        const int qt = ph ? (15 - p) : p;
        const int tileBase = qt * (qt + 1) / 2;
        f32x4 acc[4][2] = {};
        bf16x8 vreg[4], preg[8];

        // preload st=0 into regs
#pragma unroll
        for (int j = 0; j < 4; ++j) {
            int idx = tid + j * 256;
            int e = idx >> 4, sc = idx & 15;
            vreg[j] = *(const bf16x8*)&vtBase[(size_t)e * T_DIM + sc * 8];
        }
        {
            const __bf16* pb = Pg + ((size_t)(b * NTILE + tileBase)) * 128 * 128;
#pragma unroll
            for (int j = 0; j < 8; ++j) {
                int idx = tid + j * 256;
                int q = idx >> 4, sc = idx & 15;
                preg[j] = *(const bf16x8*)&pb[q * 128 + sc * 8];
            }
        }
        __syncthreads();   // protect LDS vs previous phase's epilogue reads
#pragma unroll
        for (int j = 0; j < 4; ++j) {
            int idx = tid + j * 256;
            *(bf16x8*)&vts[(idx >> 4) * 136 + (idx & 15) * 8] = vreg[j];
        }
#pragma unroll
        for (int j = 0; j < 8; ++j) {
            int idx = tid + j * 256;
            *(bf16x8*)&ps[(idx >> 4) * 136 + (idx & 15) * 8] = preg[j];
        }
        __syncthreads();

        for (int st = 0; st <= qt; ++st) {
            if (st < qt) {
                // issue next tile's loads (latency hides under MFMA below)
#pragma unroll
                for (int j = 0; j < 4; ++j) {
                    int idx = tid + j * 256;
                    int e = idx >> 4, sc = idx & 15;
                    vreg[j] = *(const bf16x8*)&vtBase[(size_t)e * T_DIM +
                                                      (st + 1) * 128 + sc * 8];
                }
                const __bf16* pb =
                    Pg + ((size_t)(b * NTILE + tileBase + st + 1)) * 128 * 128;
#pragma unroll
                for (int j = 0; j < 8; ++j) {
                    int idx = tid + j * 256;
                    int q = idx >> 4, sc = idx & 15;
                    preg[j] = *(const bf16x8*)&pb[q * 128 + sc * 8];
                }
            }
#pragma unroll
            for (int kit = 0; kit < 4; ++kit) {
                bf16x8 bfr[2];
#pragma unroll
                for (int nt = 0; nt < 2; ++nt) {
                    int q = w * 32 + nt * 16 + qL;
                    bfr[nt] = *(const bf16x8*)&ps[q * 136 + kit * 32 + quad * 8];
                }
#pragma unroll
                for (int mt = 0; mt < 4; ++mt) {
                    bf16x8 af = *(const bf16x8*)&vts[(mt * 16 + qL) * 136 + kit * 32 + quad * 8];
#pragma unroll
                    for (int nt = 0; nt < 2; ++nt)
                        acc[mt][nt] = __builtin_amdgcn_mfma_f32_16x16x32_bf16(
                            af, bfr[nt], acc[mt][nt], 0, 0, 0);
                }
            }
            if (st < qt) {
                __syncthreads();
#pragma unroll
                for (int j = 0; j < 4; ++j) {
                    int idx = tid + j * 256;
                    *(bf16x8*)&vts[(idx >> 4) * 136 + (idx & 15) * 8] = vreg[j];
                }
#pragma unroll
                for (int j = 0; j < 8; ++j) {
                    int idx = tid + j * 256;
                    *(bf16x8*)&ps[(idx >> 4) * 136 + (idx & 15) * 8] = preg[j];
                }
                __syncthreads();
            }
        }
        __syncthreads();   // compute done; reuse vts as per-wave transpose scratch

        float* tb = (float*)vts + w * 640;     // [32 q][20 e-slots]
#pragma unroll
        for (int mt = 0; mt < 4; ++mt) {
#pragma unroll
            for (int nt = 0; nt < 2; ++nt)
                *(f32x4*)&tb[(nt * 16 + qL) * 20 + quad * 4] = acc[mt][nt];
#pragma unroll
            for (int j = 0; j < 2; ++j) {
                int fid = lane + j * 64;       // 128 float4 = 32q x 16e
                int q = fid >> 2, e4 = fid & 3;
                float4 val = *(const float4*)&tb[q * 20 + e4 * 4];
                int t = qt * 128 + w * 32 + q;
                float sca = rsqrtf((float)(t + 1));
                float4 r = {val.x * sca, val.y * sca, val.z * sca, val.w * sca};
                *(float4*)&OUT[((size_t)t * B_DIM + b) * E_DIM + es * 64 + mt * 16 + e4 * 4] = r;
            }
        }
    }
}

// ---------------------------------------------------------------------------
extern "C" void kernel_launch(void* const* d_in, const int* in_sizes, int n_in,
                              void* d_out, int out_size, void* d_ws,
                              size_t ws_size, hipStream_t stream) {
    const float* x = (const float*)d_in[0];
    const float* Wq = (const float*)d_in[2];
    const float* bq = (const float*)d_in[3];
    const float* Wk = (const float*)d_in[4];
    const float* bk = (const float*)d_in[5];
    const float* Wv = (const float*)d_in[6];
    const float* bv = (const float*)d_in[7];
    const float* kg = (const float*)d_in[8];
    const float* kb = (const float*)d_in[9];
    const float* vg = (const float*)d_in[10];
    const float* vb = (const float*)d_in[11];
    float* out = (float*)d_out;

    char* base = (char*)d_ws;
    const size_t MB = 1024 * 1024;
    __bf16* qb    = (__bf16*)(base + 0);         // [r][e] bf16, 8 MB
    __bf16* vbuf  = (__bf16*)(base + 8 * MB);    // [r][e] bf16, 8 MB
    float*  kraw  = (float*)(base + 16 * MB);    // [r][64] fp32, 1 MB
    __bf16* xb    = (__bf16*)(base + 17 * MB);   // 8 MB
    __bf16* wb    = (__bf16*)(base + 25 * MB);   // 4.46 MB
    __bf16* qnb   = (__bf16*)(base + 30 * MB);   // [b][t][64], 0.5 MB
    __bf16* knb   = (__bf16*)(base + 31 * MB);   // [b][t][64], 0.5 MB
    float2* stats = (float2*)(base + 32 * MB);   // 32 KB
    // aliases of dead regions:
    __bf16* Pg  = (__bf16*)(base + 0);           // 8.9 MB (qb+vbuf dead after transpose)
    __bf16* vbT = xb;                            // [b][e][t], 8 MB (xb dead after gemm)

    cvt_all<<<dim3(2048 + WROWS * 1024 / 2048), 256, 0, stream>>>(x, Wq, Wv, Wk, xb, wb);
    gemm_mfma<<<dim3(32, 33), 256, 0, stream>>>(xb, wb, bq, bv, bk, qb, vbuf, kraw);
    rowops<<<dim3(R_DIM), 256, 0, stream>>>(qb, kraw, vbuf, kg, kb, qnb, knb, stats);
    transpose_lnv<<<dim3(T_DIM / 64, E_DIM / 64, B_DIM), 256, 0, stream>>>(
        vbuf, stats, vg, vb, vbT);
    scoreK<<<dim3(NTILE, B_DIM), 256, 0, stream>>>(qnb, knb, Pg);
    flashPV<<<dim3(8, 16, B_DIM), 256, 0, stream>>>(Pg, vbT, out);
}

// Round 10
// 182.272 us; speedup vs baseline: 1.0370x; 1.0370x over previous
//
#include <hip/hip_runtime.h>
#include <math.h>

#define T_DIM 2048
#define B_DIM 2
#define E_DIM 1024
#define K_DIM 64
#define H_DIM 16
#define R_DIM (T_DIM * B_DIM)   // 4096 rows, row r = t*B + b
#define WROWS 2176              // Wq(1024) + Wv(1024) + Wk(64) + pad(64)
#define NTILE 136               // 16*17/2 causal (qt,st) tile pairs

typedef __bf16 bf16x8 __attribute__((ext_vector_type(8)));
typedef __bf16 bf16x4 __attribute__((ext_vector_type(4)));
typedef float f32x4 __attribute__((ext_vector_type(4)));

#define GLD16(gptr, lptr)                                                      \
    __builtin_amdgcn_global_load_lds(                                          \
        (const __attribute__((address_space(1))) void*)(gptr),                 \
        (__attribute__((address_space(3))) void*)(lptr), 16, 0, 0)

// ---------------------------------------------------------------------------
// Fused fp32->bf16 conversion: blocks [0,2048) convert x (4M elems);
// blocks [2048,3136) convert W-concat [Wq;Wv;Wk;pad] (2176*1024 elems).
// ---------------------------------------------------------------------------
__global__ __launch_bounds__(256) void cvt_all(const float* __restrict__ X,
                                               const float* __restrict__ Wq,
                                               const float* __restrict__ Wv,
                                               const float* __restrict__ Wk,
                                               __bf16* __restrict__ XB,
                                               __bf16* __restrict__ WB) {
    const size_t nq = (size_t)1024 * 1024;
    const size_t nk = (size_t)64 * 1024;
    bf16x8 o;
    if (blockIdx.x < 2048) {
        size_t g = ((size_t)blockIdx.x * 256 + threadIdx.x) * 8;
        float4 a = *(const float4*)&X[g];
        float4 b = *(const float4*)&X[g + 4];
        o[0] = (__bf16)a.x; o[1] = (__bf16)a.y; o[2] = (__bf16)a.z; o[3] = (__bf16)a.w;
        o[4] = (__bf16)b.x; o[5] = (__bf16)b.y; o[6] = (__bf16)b.z; o[7] = (__bf16)b.w;
        *(bf16x8*)&XB[g] = o;
    } else {
        size_t g = ((size_t)(blockIdx.x - 2048) * 256 + threadIdx.x) * 8;
        if (g < 2 * nq + nk) {
            const float* src;
            size_t off;
            if (g < nq)          { src = Wq; off = g; }
            else if (g < 2 * nq) { src = Wv; off = g - nq; }
            else                 { src = Wk; off = g - 2 * nq; }
            float4 a = *(const float4*)&src[off];
            float4 b = *(const float4*)&src[off + 4];
            o[0] = (__bf16)a.x; o[1] = (__bf16)a.y; o[2] = (__bf16)a.z; o[3] = (__bf16)a.w;
            o[4] = (__bf16)b.x; o[5] = (__bf16)b.y; o[6] = (__bf16)b.z; o[7] = (__bf16)b.w;
        } else {
#pragma unroll
            for (int i = 0; i < 8; ++i) o[i] = (__bf16)0.f;
        }
        *(bf16x8*)&WB[g] = o;
    }
}

// ---------------------------------------------------------------------------
// bf16 MFMA GEMM (round-8 proven): C[4096 x 2176] = XB @ WB^T, 128x128 tiles,
// BK=32 (stride-32 LDS is the only layout compatible with global_load_lds --
// padding breaks the uniform+lane*16 dest rule; stride-64 aliases all banks).
// Col tiles <1024 -> Qb bf16(+bq); <2048 -> Vb bf16(+bv); else 64 -> Kr fp32.
// ---------------------------------------------------------------------------
__global__ __launch_bounds__(256) void gemm_mfma(const __bf16* __restrict__ XB,
                                                 const __bf16* __restrict__ WB,
                                                 const float* __restrict__ bq,
                                                 const float* __restrict__ bv,
                                                 const float* __restrict__ bk,
                                                 __bf16* __restrict__ Qb,
                                                 __bf16* __restrict__ Vb,
                                                 float* __restrict__ Kr) {
    __shared__ __bf16 Als[128 * 32];   // 8 KB
    __shared__ __bf16 Bls[128 * 32];   // 8 KB
    const int tid = threadIdx.x;
    const int lane = tid & 63;
    const int w = tid >> 6;
    const int wm = (w & 1) * 64;
    const int wn = (w >> 1) * 64;
    const int rBase = blockIdx.x * 128;
    const int cBase = blockIdx.y * 128;

    const int c0 = tid, c1 = tid + 256;
    const __bf16* gA0 = XB + (size_t)(rBase + (c0 >> 2)) * E_DIM + (c0 & 3) * 8;
    const __bf16* gA1 = XB + (size_t)(rBase + (c1 >> 2)) * E_DIM + (c1 & 3) * 8;
    const __bf16* gB0 = WB + (size_t)(cBase + (c0 >> 2)) * E_DIM + (c0 & 3) * 8;
    const __bf16* gB1 = WB + (size_t)(cBase + (c1 >> 2)) * E_DIM + (c1 & 3) * 8;
    __bf16* lA0 = Als + c0 * 8;
    __bf16* lA1 = Als + c1 * 8;
    __bf16* lB0 = Bls + c0 * 8;
    __bf16* lB1 = Bls + c1 * 8;

    const int fr = lane & 15;
    const int fk = (lane >> 4) * 8;
    const __bf16* aF = Als + (wm + fr) * 32 + fk;
    const __bf16* bF = Bls + (wn + fr) * 32 + fk;

    f32x4 acc[4][4] = {};

    for (int kk = 0; kk < E_DIM; kk += 32) {
        __syncthreads();
        GLD16(gA0 + kk, lA0);
        GLD16(gA1 + kk, lA1);
        GLD16(gB0 + kk, lB0);
        GLD16(gB1 + kk, lB1);
        __syncthreads();

        bf16x8 af[4], bfr[4];
#pragma unroll
        for (int mt = 0; mt < 4; ++mt) af[mt] = *(const bf16x8*)(aF + mt * 16 * 32);
#pragma unroll
        for (int nt = 0; nt < 4; ++nt) bfr[nt] = *(const bf16x8*)(bF + nt * 16 * 32);
#pragma unroll
        for (int mt = 0; mt < 4; ++mt)
#pragma unroll
            for (int nt = 0; nt < 4; ++nt)
                acc[mt][nt] = __builtin_amdgcn_mfma_f32_16x16x32_bf16(
                    af[mt], bfr[nt], acc[mt][nt], 0, 0, 0);
    }

    const int row0 = rBase + wm + (lane >> 4) * 4;
    if (cBase < 2048) {
        const float* bias;
        __bf16* Cout;
        int colBase;
        if (cBase < 1024) { bias = bq; Cout = Qb; colBase = cBase; }
        else              { bias = bv; Cout = Vb; colBase = cBase - 1024; }
        const int col0 = colBase + wn + (lane & 15);
#pragma unroll
        for (int mt = 0; mt < 4; ++mt)
#pragma unroll
            for (int nt = 0; nt < 4; ++nt) {
                int cc = col0 + nt * 16;
                float bb = bias[cc];
#pragma unroll
                for (int r = 0; r < 4; ++r)
                    Cout[(size_t)(row0 + mt * 16 + r) * E_DIM + cc] =
                        (__bf16)(acc[mt][nt][r] + bb);
            }
    } else {
        const int col0 = wn + (lane & 15);
#pragma unroll
        for (int mt = 0; mt < 4; ++mt)
#pragma unroll
            for (int nt = 0; nt < 4; ++nt) {
                int cc = col0 + nt * 16;
                if (cc < 64) {
                    float bb = bk[cc];
#pragma unroll
                    for (int r = 0; r < 4; ++r)
                        Kr[(size_t)(row0 + mt * 16 + r) * K_DIM + cc] =
                            acc[mt][nt][r] + bb;
                }
            }
    }
}

// ---------------------------------------------------------------------------
// Fused row epilogues, one block per row r = t*B + b:
//  - qn[b][t][k] = mean_h softmax_k(qb[r, h*64+k])
//  - knb[b][t][k] = LN64(kraw[r])
//  - stats[r] = {mean, rsqrt(var+eps)} of vb[r]
// ---------------------------------------------------------------------------
__global__ __launch_bounds__(256) void rowops(const __bf16* __restrict__ Qb,
                                              const float* __restrict__ Kraw,
                                              const __bf16* __restrict__ Vb,
                                              const float* __restrict__ kg,
                                              const float* __restrict__ kb,
                                              __bf16* __restrict__ QNB,
                                              __bf16* __restrict__ KNB,
                                              float2* __restrict__ ST) {
    const int r = blockIdx.x;
    const int tid = threadIdx.x;
    const int lane = tid & 63, wv = tid >> 6;
    const int t = r >> 1, b = r & 1;
    __shared__ float redq[4][64];
    __shared__ float redv[2][4];

    float acc = 0.f;
#pragma unroll
    for (int h4 = 0; h4 < 4; ++h4) {
        int h = wv * 4 + h4;
        float v = (float)Qb[(size_t)r * 1024 + h * 64 + lane];
        float m = v;
#pragma unroll
        for (int off = 32; off; off >>= 1) m = fmaxf(m, __shfl_xor(m, off));
        float e = expf(v - m);
        float ssum = e;
#pragma unroll
        for (int off = 32; off; off >>= 1) ssum += __shfl_xor(ssum, off);
        acc += e / ssum;
    }
    redq[wv][lane] = acc;

    {
        bf16x4 v4 = *(const bf16x4*)&Vb[(size_t)r * 1024 + tid * 4];
        float a = (float)v4[0], c = (float)v4[1], d = (float)v4[2], e = (float)v4[3];
        float s = a + c + d + e;
        float s2 = a * a + c * c + d * d + e * e;
#pragma unroll
        for (int off = 32; off; off >>= 1) {
            s += __shfl_xor(s, off);
            s2 += __shfl_xor(s2, off);
        }
        if (lane == 0) { redv[0][wv] = s; redv[1][wv] = s2; }
    }
    __syncthreads();

    if (tid < 64) {
        float s = redq[0][tid] + redq[1][tid] + redq[2][tid] + redq[3][tid];
        QNB[((size_t)b * T_DIM + t) * K_DIM + tid] = (__bf16)(s * (1.f / 16.f));
    } else if (tid < 128) {
        float v = Kraw[(size_t)r * K_DIM + lane];
        float s = v, s2 = v * v;
#pragma unroll
        for (int off = 32; off; off >>= 1) {
            s += __shfl_xor(s, off);
            s2 += __shfl_xor(s2, off);
        }
        float mean = s * (1.f / 64.f);
        float var = s2 * (1.f / 64.f) - mean * mean;
        float inv = rsqrtf(var + 1e-5f);
        KNB[((size_t)b * T_DIM + t) * K_DIM + lane] =
            (__bf16)((v - mean) * inv * kg[lane] + kb[lane]);
    } else if (tid == 128) {
        float s = redv[0][0] + redv[0][1] + redv[0][2] + redv[0][3];
        float s2 = redv[1][0] + redv[1][1] + redv[1][2] + redv[1][3];
        float mean = s * (1.f / 1024.f);
        float var = s2 * (1.f / 1024.f) - mean * mean;
        ST[r] = make_float2(mean, rsqrtf(var + 1e-5f));
    }
}

// ---------------------------------------------------------------------------
// Merged pass: blocks [0,1024) = LN+transpose of v (memory-bound);
// blocks [1024,1296) = causal score tiles (MFMA-bound). Both depend only on
// rowops outputs; merging lets them co-schedule across CUs and saves a launch.
// ---------------------------------------------------------------------------
__global__ __launch_bounds__(256) void prep_score(const __bf16* __restrict__ VB,
                                                  const float2* __restrict__ ST,
                                                  const float* __restrict__ gamma,
                                                  const float* __restrict__ beta,
                                                  __bf16* __restrict__ VT,
                                                  const __bf16* __restrict__ QNB,
                                                  const __bf16* __restrict__ KNB,
                                                  __bf16* __restrict__ Pg) {
    __shared__ __align__(16) unsigned char smem[36864];   // 36 KB union
    const int bid = blockIdx.x;
    const int tid = threadIdx.x;

    if (bid < 1024) {
        // ---- LN + transpose: vb bf16 [t*2+b][e] -> VT bf16 [b][e][t] ----
        float (*tile)[65] = (float(*)[65])smem;           // 16.6 KB
        const int tb = bid & 31, eb = (bid >> 5) & 15, b = bid >> 9;
#pragma unroll
        for (int j = 0; j < 2; ++j) {
            int idx = tid + j * 256;       // 512 chunks of 8 bf16
            int tl = idx >> 3, e8 = idx & 7;
            int r = (tb * 64 + tl) * B_DIM + b;
            float2 st = ST[r];
            bf16x8 v = *(const bf16x8*)&VB[(size_t)r * E_DIM + eb * 64 + e8 * 8];
#pragma unroll
            for (int i = 0; i < 8; ++i)
                tile[tl][e8 * 8 + i] = ((float)v[i] - st.x) * st.y;
        }
        __syncthreads();
#pragma unroll
        for (int j = 0; j < 4; ++j) {
            int idx = tid + j * 256;       // 1024 groups of 4 t
            int e = idx >> 4, t4 = idx & 15;
            float g = gamma[eb * 64 + e], bb = beta[eb * 64 + e];
            bf16x4 o;
#pragma unroll
            for (int i = 0; i < 4; ++i) o[i] = (__bf16)(tile[t4 * 4 + i][e] * g + bb);
            *(bf16x4*)&VT[((size_t)b * E_DIM + eb * 64 + e) * T_DIM + tb * 64 + t4 * 4] = o;
        }
    } else {
        // ---- scoreK: masked causal 128x128 score tile -> Pg bf16 ----
        __bf16* qns = (__bf16*)smem;                      // 128*72 = 18 KB
        __bf16* kns = (__bf16*)(smem + 18432);            // 128*72 = 18 KB
        const int idx0 = bid - 1024;
        const int b = idx0 & 1;
        const int tileId = idx0 >> 1;
        int qt = 0, rem = tileId;
        while (rem > qt) { rem -= (qt + 1); ++qt; }
        const int st = rem;
        const int lane = tid & 63;
        const int w = tid >> 6;
        const int qL = lane & 15;
        const int quad = lane >> 4;

        const __bf16* qsrc = QNB + ((size_t)b * T_DIM + qt * 128) * K_DIM;
        const __bf16* ksrc = KNB + ((size_t)b * T_DIM + st * 128) * K_DIM;
#pragma unroll
        for (int j = 0; j < 4; ++j) {
            int idx = tid + j * 256;
            int row = idx >> 3, k8 = idx & 7;
            *(bf16x8*)&qns[row * 72 + k8 * 8] = *(const bf16x8*)&qsrc[row * K_DIM + k8 * 8];
            *(bf16x8*)&kns[row * 72 + k8 * 8] = *(const bf16x8*)&ksrc[row * K_DIM + k8 * 8];
        }
        __syncthreads();

        f32x4 acc[8][2] = {};
#pragma unroll
        for (int kit = 0; kit < 2; ++kit) {
            bf16x8 bfr[2];
#pragma unroll
            for (int nt = 0; nt < 2; ++nt) {
                int q = w * 32 + nt * 16 + qL;
                bfr[nt] = *(const bf16x8*)&qns[q * 72 + kit * 32 + quad * 8];
            }
#pragma unroll
            for (int mt = 0; mt < 8; ++mt) {
                bf16x8 af = *(const bf16x8*)&kns[(mt * 16 + qL) * 72 + kit * 32 + quad * 8];
#pragma unroll
                for (int nt = 0; nt < 2; ++nt)
                    acc[mt][nt] = __builtin_amdgcn_mfma_f32_16x16x32_bf16(
                        af, bfr[nt], acc[mt][nt], 0, 0, 0);
            }
        }
        __bf16* pb = Pg + ((size_t)(b * NTILE + tileId)) * 128 * 128;
#pragma unroll
        for (int mt = 0; mt < 8; ++mt)
#pragma unroll
            for (int nt = 0; nt < 2; ++nt) {
                int q = w * 32 + nt * 16 + qL;
                int s0 = mt * 16 + quad * 4;
                bf16x4 o;
#pragma unroll
                for (int r = 0; r < 4; ++r) {
                    float val = acc[mt][nt][r];
                    if (qt == st && (s0 + r) > q) val = 0.f;
                    o[r] = (__bf16)val;
                }
                *(bf16x4*)&pb[(size_t)q * 128 + s0] = o;
            }
    }
}

// ---------------------------------------------------------------------------
// flashPV (round-8 proven): out[t,b,e] = rsqrt(t+1)*sum_{st<=qt} sum_s P·v
// Grid (8 pairs, 16 es, 2 b); pair p covers qt=p then 15-p (uniform 17 iters).
// ---------------------------------------------------------------------------
__global__ __launch_bounds__(256) void flashPV(const __bf16* __restrict__ Pg,
                                               const __bf16* __restrict__ VT,
                                               float* __restrict__ OUT) {
    __shared__ __align__(16) __bf16 vts[64 * 136];    // 17.4 KB (+ epilogue scratch)
    __shared__ __align__(16) __bf16 ps[128 * 136];    // 34.8 KB
    const int p = blockIdx.x;
    const int es = blockIdx.y;
    const int b = blockIdx.z;
    const int tid = threadIdx.x;
    const int lane = tid & 63;
    const int w = tid >> 6;
    const int qL = lane & 15;
    const int quad = lane >> 4;

    for (int ph = 0; ph < 2; ++ph) {
        const int qt = ph ? (15 - p) : p;
        const int tileBase = qt * (qt + 1) / 2;
        f32x4 acc[4][2] = {};

        for (int st = 0; st <= qt; ++st) {
            __syncthreads();
#pragma unroll
            for (int j = 0; j < 4; ++j) {
                int idx = tid + j * 256;
                int e = idx >> 4, sc = idx & 15;
                *(bf16x8*)&vts[e * 136 + sc * 8] =
                    *(const bf16x8*)&VT[((size_t)b * E_DIM + es * 64 + e) * T_DIM +
                                        st * 128 + sc * 8];
            }
            const __bf16* pb = Pg + ((size_t)(b * NTILE + tileBase + st)) * 128 * 128;
#pragma unroll
            for (int j = 0; j < 8; ++j) {
                int idx = tid + j * 256;
                int q = idx >> 4, sc = idx & 15;
                *(bf16x8*)&ps[q * 136 + sc * 8] = *(const bf16x8*)&pb[q * 128 + sc * 8];
            }
            __syncthreads();
#pragma unroll
            for (int kit = 0; kit < 4; ++kit) {
                bf16x8 bfr[2];
#pragma unroll
                for (int nt = 0; nt < 2; ++nt) {
                    int q = w * 32 + nt * 16 + qL;
                    bfr[nt] = *(const bf16x8*)&ps[q * 136 + kit * 32 + quad * 8];
                }
#pragma unroll
                for (int mt = 0; mt < 4; ++mt) {
                    bf16x8 af = *(const bf16x8*)&vts[(mt * 16 + qL) * 136 + kit * 32 + quad * 8];
#pragma unroll
                    for (int nt = 0; nt < 2; ++nt)
                        acc[mt][nt] = __builtin_amdgcn_mfma_f32_16x16x32_bf16(
                            af, bfr[nt], acc[mt][nt], 0, 0, 0);
                }
            }
        }
        __syncthreads();   // compute done; reuse vts as per-wave transpose scratch

        float* tb = (float*)vts + w * 640;     // [32 q][20 e-slots]
#pragma unroll
        for (int mt = 0; mt < 4; ++mt) {
#pragma unroll
            for (int nt = 0; nt < 2; ++nt)
                *(f32x4*)&tb[(nt * 16 + qL) * 20 + quad * 4] = acc[mt][nt];
#pragma unroll
            for (int j = 0; j < 2; ++j) {
                int fid = lane + j * 64;       // 128 float4 = 32q x 16e
                int q = fid >> 2, e4 = fid & 3;
                float4 val = *(const float4*)&tb[q * 20 + e4 * 4];
                int t = qt * 128 + w * 32 + q;
                float sca = rsqrtf((float)(t + 1));
                float4 r = {val.x * sca, val.y * sca, val.z * sca, val.w * sca};
                *(float4*)&OUT[((size_t)t * B_DIM + b) * E_DIM + es * 64 + mt * 16 + e4 * 4] = r;
            }
        }
    }
}

// ---------------------------------------------------------------------------
extern "C" void kernel_launch(void* const* d_in, const int* in_sizes, int n_in,
                              void* d_out, int out_size, void* d_ws,
                              size_t ws_size, hipStream_t stream) {
    const float* x = (const float*)d_in[0];
    const float* Wq = (const float*)d_in[2];
    const float* bq = (const float*)d_in[3];
    const float* Wk = (const float*)d_in[4];
    const float* bk = (const float*)d_in[5];
    const float* Wv = (const float*)d_in[6];
    const float* bv = (const float*)d_in[7];
    const float* kg = (const float*)d_in[8];
    const float* kb = (const float*)d_in[9];
    const float* vg = (const float*)d_in[10];
    const float* vb = (const float*)d_in[11];
    float* out = (float*)d_out;

    char* base = (char*)d_ws;
    const size_t MB = 1024 * 1024;
    __bf16* qb    = (__bf16*)(base + 0);         // [r][e] bf16, 8 MB
    __bf16* vbuf  = (__bf16*)(base + 8 * MB);    // [r][e] bf16, 8 MB
    float*  kraw  = (float*)(base + 16 * MB);    // [r][64] fp32, 1 MB
    __bf16* xb    = (__bf16*)(base + 17 * MB);   // 8 MB
    __bf16* wb    = (__bf16*)(base + 25 * MB);   // 4.46 MB
    __bf16* qnb   = (__bf16*)(base + 30 * MB);   // [b][t][64], 0.5 MB
    __bf16* knb   = (__bf16*)(base + 31 * MB);   // [b][t][64], 0.5 MB
    float2* stats = (float2*)(base + 32 * MB);   // 32 KB
    // aliases of dead regions:
    __bf16* Pg  = (__bf16*)(base + 0);           // 8.9 MB (qb+vbuf dead after prep_score reads)
    __bf16* vbT = xb;                            // [b][e][t], 8 MB (xb dead after gemm)

    cvt_all<<<dim3(2048 + WROWS * 1024 / 2048), 256, 0, stream>>>(x, Wq, Wv, Wk, xb, wb);
    gemm_mfma<<<dim3(32, 17), 256, 0, stream>>>(xb, wb, bq, bv, bk, qb, vbuf, kraw);
    rowops<<<dim3(R_DIM), 256, 0, stream>>>(qb, kraw, vbuf, kg, kb, qnb, knb, stats);
    prep_score<<<dim3(1024 + 2 * NTILE), 256, 0, stream>>>(vbuf, stats, vg, vb, vbT,
                                                           qnb, knb, Pg);
    flashPV<<<dim3(8, 16, B_DIM), 256, 0, stream>>>(Pg, vbT, out);
}